// Round 13
// baseline (400.177 us; speedup 1.0000x reference)
//
#include <hip/hip_runtime.h>

// WalkerVisitLosses, round 13.
// E = exp2(A'.B'^T) (A'=A*SF, SF^2=log2(e)/sqrt(128)); SE_i row sums,
// CS_k col sums. Ehat' = E*rsqrt(CS)*64 in fp8 e4m3; S = Ehat'.Ehat'^T;
// walker log(eps + S*(1/SE)*2^-12) on same-label tile pairs; visit from E/SE.
// Round-13:
//  k_gram: K-permuted LDS layout [c0,c4,c1,c5,c2,c6,c3,c7], LROW=80 ->
//   ONE ds_read_b128 per operand-row per iter (banks: starts 20m+4q all
//   mult-of-4, uniform 8/bank minimum; b64 layouts r10/r12 both conflicted).
//  k_stats/k_fill: ks-outer frag loads (32 live frag VGPRs vs 128) +
//   launch_bounds(256,3) -> 3 waves/SIMD (was 2, latency-bound).

typedef __attribute__((ext_vector_type(8))) short bf16x8;
typedef __attribute__((ext_vector_type(4))) float f32x4;
typedef __attribute__((ext_vector_type(2))) long longx2;

#define NROW 8192
#define DIM 128
#define NLAB 10
#define EPSf 1e-8f
#define SF 0.35709582f /* sqrt( log2(e)/sqrt(128) ) */
#define LAM 64.0f      /* fp8 range-centering scale; LAM^-2 folded into ISE */
#define ILAM2 (1.0f / 4096.0f)
#define SPLIT 4
#define NPAIR 36   /* supports up to 8 row-tiles per label */
#define SPSTRIDE (360 * 16384) /* elements per split */
#define LROW 80    /* LDS row stride bytes (fp8, 64B data + 16 pad) */

// workspace byte offsets (total ~120 MB)
#define O_WA 0
#define O_VA 8
#define O_CNT 64
#define O_OFF 128
#define O_SIDX 256
#define O_PS 33280
#define O_CS 1081856
#define O_VK 1114624
#define O_CV 1147392
#define O_CKS 1180160
#define O_ABF 1212928
#define O_BBF 3310080
#define O_E 5407232            /* fp8: 64 MB */
#define O_SP 72516096

__device__ __forceinline__ unsigned short f2bf(float f) {
  unsigned u = __builtin_bit_cast(unsigned, f);
  u += 0x7fffu + ((u >> 16) & 1u);
  return (unsigned short)(u >> 16);
}
__device__ __forceinline__ float bf2f(unsigned short s) {
  unsigned u = ((unsigned)s) << 16;
  return __builtin_bit_cast(float, u);
}
__device__ __forceinline__ unsigned char f2fp8(float f) {
  int v = __builtin_amdgcn_cvt_pk_fp8_f32(f, f, 0, false);
  return (unsigned char)(v & 0xff);
}

__global__ __launch_bounds__(256) void k_bucket(const int* __restrict__ lab,
                                                int* cnt, int* offs, int* sidx,
                                                double* wa, double* va,
                                                float* cs, float* vk) {
  __shared__ int lc[NLAB], lcur[NLAB];
  int tid = threadIdx.x;
  if (tid < NLAB) lc[tid] = 0;
  __syncthreads();
  for (int i = tid; i < NROW; i += 256) {
    int l = lab[i]; l = l < 0 ? 0 : (l > 9 ? 9 : l);
    atomicAdd(&lc[l], 1);
  }
  for (int i = tid; i < NROW; i += 256) { cs[i] = 0.f; vk[i] = 0.f; }
  __syncthreads();
  if (tid == 0) {
    int run = 0;
    for (int l = 0; l < NLAB; ++l) { cnt[l] = lc[l]; offs[l] = run; lcur[l] = run; run += lc[l]; }
    *wa = 0.0; *va = 0.0;
  }
  __syncthreads();
  for (int i = tid; i < NROW; i += 256) {
    int l = lab[i]; l = l < 0 ? 0 : (l > 9 ? 9 : l);
    int p = atomicAdd(&lcur[l], 1);
    sidx[p] = i;
  }
}

__global__ __launch_bounds__(256) void k_convert(const float* __restrict__ X,
                                                 unsigned short* __restrict__ Y) {
  int i = (blockIdx.x * 256 + threadIdx.x) * 8;
  f32x4 a = *(const f32x4*)(X + i);
  f32x4 b = *(const f32x4*)(X + i + 4);
  bf16x8 o;
  o[0] = (short)f2bf(a[0] * SF); o[1] = (short)f2bf(a[1] * SF);
  o[2] = (short)f2bf(a[2] * SF); o[3] = (short)f2bf(a[3] * SF);
  o[4] = (short)f2bf(b[0] * SF); o[5] = (short)f2bf(b[1] * SF);
  o[6] = (short)f2bf(b[2] * SF); o[7] = (short)f2bf(b[3] * SF);
  *(bf16x8*)(Y + i) = o;
}

// Pass 1: GEMM+exp only -> row partial sums (ps, 32 slices) + col sums (atomic).
// ks-outer frag loads: 32 live frag VGPRs instead of 128.
__global__ __launch_bounds__(256, 3) void k_stats(const unsigned short* __restrict__ Abf,
                                                  const unsigned short* __restrict__ Bbf,
                                                  const int* __restrict__ sidx,
                                                  float* __restrict__ ps,
                                                  float* __restrict__ CS) {
  __shared__ int gidx[128];
  int tid = threadIdx.x;
  if (tid < 128) gidx[tid] = sidx[blockIdx.x * 128 + tid];
  __syncthreads();
  int wave = tid >> 6, lane = tid & 63;
  int wrow = wave >> 1, wcol = wave & 1;
  int m = lane & 15, quad = lane >> 4;
  int gi[4];
#pragma unroll
  for (int mi = 0; mi < 4; ++mi) gi[mi] = gidx[wrow * 64 + mi * 16 + m];
  float tsum[4][4];
#pragma unroll
  for (int mi = 0; mi < 4; ++mi)
#pragma unroll
    for (int r = 0; r < 4; ++r) tsum[mi][r] = 0.f;
  int p0 = blockIdx.x * 128 + wrow * 64;
  for (int t = 0; t < 4; ++t) {
    int c0 = blockIdx.y * 512 + t * 128 + wcol * 64;
    f32x4 acc[4][4];
#pragma unroll
    for (int mi = 0; mi < 4; ++mi)
#pragma unroll
      for (int ni = 0; ni < 4; ++ni) acc[mi][ni] = (f32x4){0.f, 0.f, 0.f, 0.f};
#pragma unroll
    for (int ks = 0; ks < 4; ++ks) {
      bf16x8 af[4], bfr[4];
#pragma unroll
      for (int mi = 0; mi < 4; ++mi)
        af[mi] = *(const bf16x8*)(Abf + gi[mi] * DIM + ks * 32 + quad * 8);
#pragma unroll
      for (int ni = 0; ni < 4; ++ni)
        bfr[ni] = *(const bf16x8*)(Bbf + (c0 + ni * 16 + m) * DIM + ks * 32 + quad * 8);
#pragma unroll
      for (int mi = 0; mi < 4; ++mi)
#pragma unroll
        for (int ni = 0; ni < 4; ++ni)
          acc[mi][ni] = __builtin_amdgcn_mfma_f32_16x16x32_bf16(af[mi], bfr[ni], acc[mi][ni], 0, 0, 0);
    }
    float csum[4] = {0.f, 0.f, 0.f, 0.f};
#pragma unroll
    for (int mi = 0; mi < 4; ++mi)
#pragma unroll
      for (int ni = 0; ni < 4; ++ni)
#pragma unroll
        for (int r = 0; r < 4; ++r) {
          float e = __builtin_amdgcn_exp2f(acc[mi][ni][r]);
          tsum[mi][r] += e;
          csum[ni] += e;
        }
#pragma unroll
    for (int ni = 0; ni < 4; ++ni) {
      csum[ni] += __shfl_xor(csum[ni], 16);
      csum[ni] += __shfl_xor(csum[ni], 32);
    }
    if (lane < 16) {
#pragma unroll
      for (int ni = 0; ni < 4; ++ni) atomicAdd(&CS[c0 + ni * 16 + lane], csum[ni]);
    }
  }
#pragma unroll
  for (int off = 1; off < 16; off <<= 1)
#pragma unroll
    for (int mi = 0; mi < 4; ++mi)
#pragma unroll
      for (int r = 0; r < 4; ++r) tsum[mi][r] += __shfl_xor(tsum[mi][r], off);
  if (m == 0) {
#pragma unroll
    for (int mi = 0; mi < 4; ++mi)
#pragma unroll
      for (int r = 0; r < 4; ++r)
        ps[(blockIdx.y * 2 + wcol) * NROW + p0 + mi * 16 + quad * 4 + r] = tsum[mi][r];
  }
}

__global__ __launch_bounds__(256) void k_mstats(const float* __restrict__ ps,
                                                const float* __restrict__ CS,
                                                float* __restrict__ CVs,
                                                float* __restrict__ CKS) {
  int i = blockIdx.x * 256 + threadIdx.x;
  float s = 0.f;
#pragma unroll
  for (int t = 0; t < 32; ++t) s += ps[t * NROW + i];
  CVs[i] = 1.f / s;
  CKS[i] = rsqrtf(CS[i]);
}

// Pass 2: recompute GEMM+exp, write Ehat*LAM as fp8 e4m3 (sorted rows),
// accumulate raw visit VK[k] += E*CV[row]. ks-outer frag loads.
__global__ __launch_bounds__(256, 3) void k_fill(const unsigned short* __restrict__ Abf,
                                                 const unsigned short* __restrict__ Bbf,
                                                 const int* __restrict__ sidx,
                                                 const float* __restrict__ CVs,
                                                 const float* __restrict__ CKS,
                                                 unsigned char* __restrict__ E,
                                                 float* __restrict__ VK) {
  __shared__ int gidx[128];
  int tid = threadIdx.x;
  if (tid < 128) gidx[tid] = sidx[blockIdx.x * 128 + tid];
  __syncthreads();
  int wave = tid >> 6, lane = tid & 63;
  int wrow = wave >> 1, wcol = wave & 1;
  int m = lane & 15, quad = lane >> 4;
  int p0 = blockIdx.x * 128 + wrow * 64;
  int gi[4];
  float cv16[4][4];
#pragma unroll
  for (int mi = 0; mi < 4; ++mi) {
    gi[mi] = gidx[wrow * 64 + mi * 16 + m];
#pragma unroll
    for (int r = 0; r < 4; ++r) cv16[mi][r] = CVs[p0 + mi * 16 + quad * 4 + r];
  }
  for (int t = 0; t < 4; ++t) {
    int c0 = blockIdx.y * 512 + t * 128 + wcol * 64;
    float ck4[4];
#pragma unroll
    for (int ni = 0; ni < 4; ++ni) ck4[ni] = CKS[c0 + ni * 16 + m] * LAM;
    f32x4 acc[4][4];
#pragma unroll
    for (int mi = 0; mi < 4; ++mi)
#pragma unroll
      for (int ni = 0; ni < 4; ++ni) acc[mi][ni] = (f32x4){0.f, 0.f, 0.f, 0.f};
#pragma unroll
    for (int ks = 0; ks < 4; ++ks) {
      bf16x8 af[4], bfr[4];
#pragma unroll
      for (int mi = 0; mi < 4; ++mi)
        af[mi] = *(const bf16x8*)(Abf + gi[mi] * DIM + ks * 32 + quad * 8);
#pragma unroll
      for (int ni = 0; ni < 4; ++ni)
        bfr[ni] = *(const bf16x8*)(Bbf + (c0 + ni * 16 + m) * DIM + ks * 32 + quad * 8);
#pragma unroll
      for (int mi = 0; mi < 4; ++mi)
#pragma unroll
        for (int ni = 0; ni < 4; ++ni)
          acc[mi][ni] = __builtin_amdgcn_mfma_f32_16x16x32_bf16(af[mi], bfr[ni], acc[mi][ni], 0, 0, 0);
    }
    float csum[4] = {0.f, 0.f, 0.f, 0.f};
#pragma unroll
    for (int mi = 0; mi < 4; ++mi)
#pragma unroll
      for (int ni = 0; ni < 4; ++ni)
#pragma unroll
        for (int r = 0; r < 4; ++r) {
          float e = __builtin_amdgcn_exp2f(acc[mi][ni][r]);
          int row = p0 + mi * 16 + quad * 4 + r;
          E[(size_t)row * NROW + c0 + ni * 16 + m] = f2fp8(e * ck4[ni]);
          csum[ni] = fmaf(e, cv16[mi][r], csum[ni]);
        }
#pragma unroll
    for (int ni = 0; ni < 4; ++ni) {
      csum[ni] += __shfl_xor(csum[ni], 16);
      csum[ni] += __shfl_xor(csum[ni], 32);
    }
    if (lane < 16) {
#pragma unroll
      for (int ni = 0; ni < 4; ++ni) atomicAdd(&VK[c0 + ni * 16 + lane], csum[ni]);
    }
  }
}

__global__ __launch_bounds__(256) void k_vloss(const float* __restrict__ VK, double* va) {
  __shared__ float red[4];
  int tid = threadIdx.x;
  int i = blockIdx.x * 256 + tid;
  float l = __logf(EPSf + VK[i] * (1.f / 8192.f));
#pragma unroll
  for (int off = 32; off; off >>= 1) l += __shfl_down(l, off);
  if ((tid & 63) == 0) red[tid >> 6] = l;
  __syncthreads();
  if (tid == 0) {
    double tot = (double)red[0] + (double)red[1] + (double)red[2] + (double)red[3];
    atomicAdd(va, -tot / 8192.0);
  }
}

// Per-label symmetric Gram on fp8 Ehat', split-K. Tile pair (ti<=tj), 128x128,
// BK=64 (8B staging loads — no spill); LDS: LROW=80, chunks K-permuted
// [c0,c4,c1,c5,c2,c6,c3,c7] so lane (m,quad) reads BOTH ks fragments with one
// ds_read_b128 at row*80+quad*16 (bank starts 20m+4q: uniform, minimal).
__global__ __launch_bounds__(256, 4) void k_gram(const unsigned char* __restrict__ Eh,
                                                 const int* __restrict__ cnt,
                                                 const int* __restrict__ offs,
                                                 unsigned short* __restrict__ Spart) {
  int gid = blockIdx.x;                // 0..1439
  int xcd = gid & 7, slot = gid >> 3;  // slot 0..179
  int group = xcd * 5 + slot / NPAIR;  // 0..39
  int pidx = slot % NPAIR;
  int lab = group / SPLIT, split = group % SPLIT;
  int tj = 0;
  while ((tj + 1) * (tj + 2) / 2 <= pidx) ++tj;
  int ti = pidx - tj * (tj + 1) / 2;
  int c = cnt[lab], o = offs[lab];
  if (tj * 128 >= c) return;
  const bool diag = (ti == tj);
  __shared__ __align__(16) unsigned char Pt[128 * LROW];
  __shared__ __align__(16) unsigned char Rt[128 * LROW];
  int tid = threadIdx.x;
  int wave = tid >> 6, lane = tid & 63;
  int wrow = wave >> 1, wcol = wave & 1;
  int m = lane & 15, quad = lane >> 4;
  const unsigned char* pp[4];
  const unsigned char* pr[4];
  int lo[4];
#pragma unroll
  for (int v = 0; v < 4; ++v) {
    int slotv = v * 256 + tid, row = slotv >> 3, c8 = slotv & 7;
    int ri = o + ti * 128 + row; if (ri > NROW - 1) ri = NROW - 1;
    int rj = o + tj * 128 + row; if (rj > NROW - 1) rj = NROW - 1;
    pp[v] = Eh + (size_t)ri * NROW + split * 2048 + c8 * 8;
    pr[v] = Eh + (size_t)rj * NROW + split * 2048 + c8 * 8;
    int pos = (c8 & 3) * 2 + (c8 >> 2);  // K-permutation [c0,c4,c1,c5,c2,c6,c3,c7]
    lo[v] = row * LROW + pos * 8;
  }
  f32x4 acc[4][4];
#pragma unroll
  for (int mi = 0; mi < 4; ++mi)
#pragma unroll
    for (int ni = 0; ni < 4; ++ni) acc[mi][ni] = (f32x4){0.f, 0.f, 0.f, 0.f};
  const unsigned char* Bt = diag ? Pt : Rt;
  for (int t = 0; t < 32; ++t) {
    __syncthreads();
    unsigned long dp[4], dr[4];
#pragma unroll
    for (int v = 0; v < 4; ++v) {
      dp[v] = *(const unsigned long*)(pp[v]); pp[v] += 64;
      if (!diag) { dr[v] = *(const unsigned long*)(pr[v]); pr[v] += 64; }
    }
#pragma unroll
    for (int v = 0; v < 4; ++v) {
      *(unsigned long*)(Pt + lo[v]) = dp[v];
      if (!diag) *(unsigned long*)(Rt + lo[v]) = dr[v];
    }
    __syncthreads();
    longx2 pa[4], rb[4];
#pragma unroll
    for (int mi = 0; mi < 4; ++mi) {
      int row = wrow * 64 + mi * 16 + m;
      pa[mi] = *(const longx2*)(Pt + row * LROW + quad * 16);
    }
#pragma unroll
    for (int ni = 0; ni < 4; ++ni) {
      int row = wcol * 64 + ni * 16 + m;
      rb[ni] = *(const longx2*)(Bt + row * LROW + quad * 16);
    }
#pragma unroll
    for (int mi = 0; mi < 4; ++mi)
#pragma unroll
      for (int ni = 0; ni < 4; ++ni)
        acc[mi][ni] = __builtin_amdgcn_mfma_f32_16x16x32_fp8_fp8(pa[mi][0], rb[ni][0], acc[mi][ni], 0, 0, 0);
#pragma unroll
    for (int mi = 0; mi < 4; ++mi)
#pragma unroll
      for (int ni = 0; ni < 4; ++ni)
        acc[mi][ni] = __builtin_amdgcn_mfma_f32_16x16x32_fp8_fp8(pa[mi][1], rb[ni][1], acc[mi][ni], 0, 0, 0);
  }
  // layout: base + (mi*4+ni)*1024 + tid*4 + r  (ushort4-packed stores)
  size_t base = (size_t)(split * SPSTRIDE) + (size_t)(lab * NPAIR + pidx) * 16384;
#pragma unroll
  for (int mi = 0; mi < 4; ++mi)
#pragma unroll
    for (int ni = 0; ni < 4; ++ni) {
      ushort4 w4;
      w4.x = f2bf(acc[mi][ni][0]);
      w4.y = f2bf(acc[mi][ni][1]);
      w4.z = f2bf(acc[mi][ni][2]);
      w4.w = f2bf(acc[mi][ni][3]);
      *(ushort4*)(Spart + base + (size_t)(mi * 4 + ni) * 1024 + tid * 4) = w4;
    }
}

// Sum split partials, apply log(eps + S * ISE * LAM^-2), accumulate walker loss.
__global__ __launch_bounds__(256) void k_reduce(const unsigned short* __restrict__ Spart,
                                                const int* __restrict__ cnt,
                                                const int* __restrict__ offs,
                                                const float* __restrict__ CVs,
                                                double* wa) {
  int lab = blockIdx.y, pidx = blockIdx.x;
  int tj = 0;
  while ((tj + 1) * (tj + 2) / 2 <= pidx) ++tj;
  int ti = pidx - tj * (tj + 1) / 2;
  int c = cnt[lab], o = offs[lab];
  if (tj * 128 >= c) return;
  __shared__ float isei[128], isej[128];
  __shared__ float red[4];
  int tid = threadIdx.x;
  if (tid < 128) {
    int ri = o + ti * 128 + tid; if (ri > NROW - 1) ri = NROW - 1;
    int rj = o + tj * 128 + tid; if (rj > NROW - 1) rj = NROW - 1;
    isei[tid] = CVs[ri] * ILAM2;
    isej[tid] = CVs[rj] * ILAM2;
  }
  __syncthreads();
  int wave = tid >> 6, lane = tid & 63;
  int wrow = wave >> 1, wcol = wave & 1;
  int m = lane & 15, quad = lane >> 4;
  size_t base = (size_t)(lab * NPAIR + pidx) * 16384;
  float lsum = 0.f;
#pragma unroll
  for (int mi = 0; mi < 4; ++mi)
#pragma unroll
    for (int ni = 0; ni < 4; ++ni) {
      size_t off = base + (size_t)(mi * 4 + ni) * 1024 + tid * 4;
      ushort4 s0 = *(const ushort4*)(Spart + off);
      ushort4 s1 = *(const ushort4*)(Spart + SPSTRIDE + off);
      ushort4 s2 = *(const ushort4*)(Spart + 2 * (size_t)SPSTRIDE + off);
      ushort4 s3 = *(const ushort4*)(Spart + 3 * (size_t)SPSTRIDE + off);
      float S[4];
      S[0] = bf2f(s0.x) + bf2f(s1.x) + bf2f(s2.x) + bf2f(s3.x);
      S[1] = bf2f(s0.y) + bf2f(s1.y) + bf2f(s2.y) + bf2f(s3.y);
      S[2] = bf2f(s0.z) + bf2f(s1.z) + bf2f(s2.z) + bf2f(s3.z);
      S[3] = bf2f(s0.w) + bf2f(s1.w) + bf2f(s2.w) + bf2f(s3.w);
      int jl = wcol * 64 + ni * 16 + m;
      int j = tj * 128 + jl;
#pragma unroll
      for (int r = 0; r < 4; ++r) {
        int il = wrow * 64 + mi * 16 + quad * 4 + r;
        int i = ti * 128 + il;
        if (i < c && j < c) {
          lsum += __logf(EPSf + S[r] * isei[il]);
          if (ti != tj) lsum += __logf(EPSf + S[r] * isej[jl]);
        }
      }
    }
#pragma unroll
  for (int off2 = 32; off2; off2 >>= 1) lsum += __shfl_down(lsum, off2);
  if (lane == 0) red[wave] = lsum;
  __syncthreads();
  if (tid == 0) {
    double tot = (double)red[0] + (double)red[1] + (double)red[2] + (double)red[3];
    atomicAdd(wa, -tot / (8192.0 * (double)c));
  }
}

__global__ void k_finish(const double* wa, const double* va, float* out) {
  out[0] = (float)(*wa);
  out[1] = (float)(*va);
}

extern "C" void kernel_launch(void* const* d_in, const int* in_sizes, int n_in,
                              void* d_out, int out_size, void* d_ws, size_t ws_size,
                              hipStream_t stream) {
  const float* A = (const float*)d_in[0];
  const float* B = (const float*)d_in[1];
  const int* LAB = (const int*)d_in[2];
  float* out = (float*)d_out;
  char* w = (char*)d_ws;
  double* WA = (double*)(w + O_WA);
  double* VA = (double*)(w + O_VA);
  int* CNT = (int*)(w + O_CNT);
  int* OFFS = (int*)(w + O_OFF);
  int* SIDX = (int*)(w + O_SIDX);
  float* PS = (float*)(w + O_PS);
  float* CS = (float*)(w + O_CS);
  float* VK = (float*)(w + O_VK);
  float* CVs = (float*)(w + O_CV);
  float* CKS = (float*)(w + O_CKS);
  unsigned short* ABF = (unsigned short*)(w + O_ABF);
  unsigned short* BBF = (unsigned short*)(w + O_BBF);
  unsigned char* E = (unsigned char*)(w + O_E);
  unsigned short* SP = (unsigned short*)(w + O_SP);

  k_bucket<<<1, 256, 0, stream>>>(LAB, CNT, OFFS, SIDX, WA, VA, CS, VK);
  k_convert<<<512, 256, 0, stream>>>(A, ABF);
  k_convert<<<512, 256, 0, stream>>>(B, BBF);
  k_stats<<<dim3(64, 16), 256, 0, stream>>>(ABF, BBF, SIDX, PS, CS);
  k_mstats<<<32, 256, 0, stream>>>(PS, CS, CVs, CKS);
  k_fill<<<dim3(64, 16), 256, 0, stream>>>(ABF, BBF, SIDX, CVs, CKS, E, VK);
  k_vloss<<<32, 256, 0, stream>>>(VK, VA);
  k_gram<<<NPAIR * SPLIT * NLAB, 256, 0, stream>>>(E, CNT, OFFS, SP);
  k_reduce<<<dim3(NPAIR, NLAB), 256, 0, stream>>>(SP, CNT, OFFS, CVs, WA);
  k_finish<<<1, 1, 0, stream>>>(WA, VA, out);
}

// Round 14
// 296.797 us; speedup vs baseline: 1.3483x; 1.3483x over previous
//
#include <hip/hip_runtime.h>

// WalkerVisitLosses, round 14.
// E = exp2(A'.B'^T) (A'=A*SF, SF^2=log2(e)/sqrt(128)); SE_i row sums,
// CS_k col sums. Ehat' = E*rsqrt(CS)*64 in fp8 e4m3; S = Ehat'.Ehat'^T;
// walker log(eps + S*(1/SE)*2^-12) on same-label tile pairs; visit from E/SE.
// Round-14: REVERT k_stats/k_fill to round-12 form (r13's ks-outer reload
// blew FETCH to 114MB/dispatch and serialized loads: fill 78->136us).
// KEEP r13 k_gram (K-permuted b128 frag reads, LROW=80) to get its counters.

typedef __attribute__((ext_vector_type(8))) short bf16x8;
typedef __attribute__((ext_vector_type(4))) float f32x4;
typedef __attribute__((ext_vector_type(2))) long longx2;

#define NROW 8192
#define DIM 128
#define NLAB 10
#define EPSf 1e-8f
#define SF 0.35709582f /* sqrt( log2(e)/sqrt(128) ) */
#define LAM 64.0f      /* fp8 range-centering scale; LAM^-2 folded into ISE */
#define ILAM2 (1.0f / 4096.0f)
#define SPLIT 4
#define NPAIR 36   /* supports up to 8 row-tiles per label */
#define SPSTRIDE (360 * 16384) /* elements per split */
#define LROW 80    /* LDS row stride bytes (fp8, 64B data + 16 pad) */

// workspace byte offsets (total ~120 MB)
#define O_WA 0
#define O_VA 8
#define O_CNT 64
#define O_OFF 128
#define O_SIDX 256
#define O_PS 33280
#define O_CS 1081856
#define O_VK 1114624
#define O_CV 1147392
#define O_CKS 1180160
#define O_ABF 1212928
#define O_BBF 3310080
#define O_E 5407232            /* fp8: 64 MB */
#define O_SP 72516096

__device__ __forceinline__ unsigned short f2bf(float f) {
  unsigned u = __builtin_bit_cast(unsigned, f);
  u += 0x7fffu + ((u >> 16) & 1u);
  return (unsigned short)(u >> 16);
}
__device__ __forceinline__ float bf2f(unsigned short s) {
  unsigned u = ((unsigned)s) << 16;
  return __builtin_bit_cast(float, u);
}
__device__ __forceinline__ unsigned char f2fp8(float f) {
  int v = __builtin_amdgcn_cvt_pk_fp8_f32(f, f, 0, false);
  return (unsigned char)(v & 0xff);
}

__global__ __launch_bounds__(256) void k_bucket(const int* __restrict__ lab,
                                                int* cnt, int* offs, int* sidx,
                                                double* wa, double* va,
                                                float* cs, float* vk) {
  __shared__ int lc[NLAB], lcur[NLAB];
  int tid = threadIdx.x;
  if (tid < NLAB) lc[tid] = 0;
  __syncthreads();
  for (int i = tid; i < NROW; i += 256) {
    int l = lab[i]; l = l < 0 ? 0 : (l > 9 ? 9 : l);
    atomicAdd(&lc[l], 1);
  }
  for (int i = tid; i < NROW; i += 256) { cs[i] = 0.f; vk[i] = 0.f; }
  __syncthreads();
  if (tid == 0) {
    int run = 0;
    for (int l = 0; l < NLAB; ++l) { cnt[l] = lc[l]; offs[l] = run; lcur[l] = run; run += lc[l]; }
    *wa = 0.0; *va = 0.0;
  }
  __syncthreads();
  for (int i = tid; i < NROW; i += 256) {
    int l = lab[i]; l = l < 0 ? 0 : (l > 9 ? 9 : l);
    int p = atomicAdd(&lcur[l], 1);
    sidx[p] = i;
  }
}

__global__ __launch_bounds__(256) void k_convert(const float* __restrict__ X,
                                                 unsigned short* __restrict__ Y) {
  int i = (blockIdx.x * 256 + threadIdx.x) * 8;
  f32x4 a = *(const f32x4*)(X + i);
  f32x4 b = *(const f32x4*)(X + i + 4);
  bf16x8 o;
  o[0] = (short)f2bf(a[0] * SF); o[1] = (short)f2bf(a[1] * SF);
  o[2] = (short)f2bf(a[2] * SF); o[3] = (short)f2bf(a[3] * SF);
  o[4] = (short)f2bf(b[0] * SF); o[5] = (short)f2bf(b[1] * SF);
  o[6] = (short)f2bf(b[2] * SF); o[7] = (short)f2bf(b[3] * SF);
  *(bf16x8*)(Y + i) = o;
}

// Pass 1: GEMM+exp only -> row partial sums (ps, 32 slices) + col sums (atomic).
// Round-12 form: hoisted af[4][4], ks-inner.
__global__ __launch_bounds__(256, 2) void k_stats(const unsigned short* __restrict__ Abf,
                                                  const unsigned short* __restrict__ Bbf,
                                                  const int* __restrict__ sidx,
                                                  float* __restrict__ ps,
                                                  float* __restrict__ CS) {
  __shared__ int gidx[128];
  int tid = threadIdx.x;
  if (tid < 128) gidx[tid] = sidx[blockIdx.x * 128 + tid];
  __syncthreads();
  int wave = tid >> 6, lane = tid & 63;
  int wrow = wave >> 1, wcol = wave & 1;
  int m = lane & 15, quad = lane >> 4;
  bf16x8 af[4][4];
#pragma unroll
  for (int mi = 0; mi < 4; ++mi) {
    int gi = gidx[wrow * 64 + mi * 16 + m];
#pragma unroll
    for (int ks = 0; ks < 4; ++ks)
      af[mi][ks] = *(const bf16x8*)(Abf + gi * DIM + ks * 32 + quad * 8);
  }
  float tsum[4][4];
#pragma unroll
  for (int mi = 0; mi < 4; ++mi)
#pragma unroll
    for (int r = 0; r < 4; ++r) tsum[mi][r] = 0.f;
  int p0 = blockIdx.x * 128 + wrow * 64;
  for (int t = 0; t < 4; ++t) {
    int c0 = blockIdx.y * 512 + t * 128 + wcol * 64;
    bf16x8 bfr[4][4];
#pragma unroll
    for (int ni = 0; ni < 4; ++ni)
#pragma unroll
      for (int ks = 0; ks < 4; ++ks)
        bfr[ni][ks] = *(const bf16x8*)(Bbf + (c0 + ni * 16 + m) * DIM + ks * 32 + quad * 8);
    f32x4 acc[4][4];
#pragma unroll
    for (int mi = 0; mi < 4; ++mi)
#pragma unroll
      for (int ni = 0; ni < 4; ++ni) acc[mi][ni] = (f32x4){0.f, 0.f, 0.f, 0.f};
#pragma unroll
    for (int ks = 0; ks < 4; ++ks)
#pragma unroll
      for (int mi = 0; mi < 4; ++mi)
#pragma unroll
        for (int ni = 0; ni < 4; ++ni)
          acc[mi][ni] = __builtin_amdgcn_mfma_f32_16x16x32_bf16(af[mi][ks], bfr[ni][ks], acc[mi][ni], 0, 0, 0);
    float csum[4] = {0.f, 0.f, 0.f, 0.f};
#pragma unroll
    for (int mi = 0; mi < 4; ++mi)
#pragma unroll
      for (int ni = 0; ni < 4; ++ni)
#pragma unroll
        for (int r = 0; r < 4; ++r) {
          float e = __builtin_amdgcn_exp2f(acc[mi][ni][r]);
          tsum[mi][r] += e;
          csum[ni] += e;
        }
#pragma unroll
    for (int ni = 0; ni < 4; ++ni) {
      csum[ni] += __shfl_xor(csum[ni], 16);
      csum[ni] += __shfl_xor(csum[ni], 32);
    }
    if (lane < 16) {
#pragma unroll
      for (int ni = 0; ni < 4; ++ni) atomicAdd(&CS[c0 + ni * 16 + lane], csum[ni]);
    }
  }
#pragma unroll
  for (int off = 1; off < 16; off <<= 1)
#pragma unroll
    for (int mi = 0; mi < 4; ++mi)
#pragma unroll
      for (int r = 0; r < 4; ++r) tsum[mi][r] += __shfl_xor(tsum[mi][r], off);
  if (m == 0) {
#pragma unroll
    for (int mi = 0; mi < 4; ++mi)
#pragma unroll
      for (int r = 0; r < 4; ++r)
        ps[(blockIdx.y * 2 + wcol) * NROW + p0 + mi * 16 + quad * 4 + r] = tsum[mi][r];
  }
}

__global__ __launch_bounds__(256) void k_mstats(const float* __restrict__ ps,
                                                const float* __restrict__ CS,
                                                float* __restrict__ CVs,
                                                float* __restrict__ CKS) {
  int i = blockIdx.x * 256 + threadIdx.x;
  float s = 0.f;
#pragma unroll
  for (int t = 0; t < 32; ++t) s += ps[t * NROW + i];
  CVs[i] = 1.f / s;
  CKS[i] = rsqrtf(CS[i]);
}

// Pass 2: recompute GEMM+exp, write Ehat*LAM as fp8 e4m3 (sorted rows),
// accumulate raw visit VK[k] += E*CV[row]. Round-12 form.
__global__ __launch_bounds__(256, 2) void k_fill(const unsigned short* __restrict__ Abf,
                                                 const unsigned short* __restrict__ Bbf,
                                                 const int* __restrict__ sidx,
                                                 const float* __restrict__ CVs,
                                                 const float* __restrict__ CKS,
                                                 unsigned char* __restrict__ E,
                                                 float* __restrict__ VK) {
  __shared__ int gidx[128];
  int tid = threadIdx.x;
  if (tid < 128) gidx[tid] = sidx[blockIdx.x * 128 + tid];
  __syncthreads();
  int wave = tid >> 6, lane = tid & 63;
  int wrow = wave >> 1, wcol = wave & 1;
  int m = lane & 15, quad = lane >> 4;
  int p0 = blockIdx.x * 128 + wrow * 64;
  bf16x8 af[4][4];
  float cv16[4][4];
#pragma unroll
  for (int mi = 0; mi < 4; ++mi) {
    int gi = gidx[wrow * 64 + mi * 16 + m];
#pragma unroll
    for (int ks = 0; ks < 4; ++ks)
      af[mi][ks] = *(const bf16x8*)(Abf + gi * DIM + ks * 32 + quad * 8);
#pragma unroll
    for (int r = 0; r < 4; ++r) cv16[mi][r] = CVs[p0 + mi * 16 + quad * 4 + r];
  }
  for (int t = 0; t < 4; ++t) {
    int c0 = blockIdx.y * 512 + t * 128 + wcol * 64;
    bf16x8 bfr[4][4];
    float ck4[4];
#pragma unroll
    for (int ni = 0; ni < 4; ++ni) {
      ck4[ni] = CKS[c0 + ni * 16 + m] * LAM;
#pragma unroll
      for (int ks = 0; ks < 4; ++ks)
        bfr[ni][ks] = *(const bf16x8*)(Bbf + (c0 + ni * 16 + m) * DIM + ks * 32 + quad * 8);
    }
    f32x4 acc[4][4];
#pragma unroll
    for (int mi = 0; mi < 4; ++mi)
#pragma unroll
      for (int ni = 0; ni < 4; ++ni) acc[mi][ni] = (f32x4){0.f, 0.f, 0.f, 0.f};
#pragma unroll
    for (int ks = 0; ks < 4; ++ks)
#pragma unroll
      for (int mi = 0; mi < 4; ++mi)
#pragma unroll
        for (int ni = 0; ni < 4; ++ni)
          acc[mi][ni] = __builtin_amdgcn_mfma_f32_16x16x32_bf16(af[mi][ks], bfr[ni][ks], acc[mi][ni], 0, 0, 0);
    float csum[4] = {0.f, 0.f, 0.f, 0.f};
#pragma unroll
    for (int mi = 0; mi < 4; ++mi)
#pragma unroll
      for (int ni = 0; ni < 4; ++ni)
#pragma unroll
        for (int r = 0; r < 4; ++r) {
          float e = __builtin_amdgcn_exp2f(acc[mi][ni][r]);
          int row = p0 + mi * 16 + quad * 4 + r;
          E[(size_t)row * NROW + c0 + ni * 16 + m] = f2fp8(e * ck4[ni]);
          csum[ni] = fmaf(e, cv16[mi][r], csum[ni]);
        }
#pragma unroll
    for (int ni = 0; ni < 4; ++ni) {
      csum[ni] += __shfl_xor(csum[ni], 16);
      csum[ni] += __shfl_xor(csum[ni], 32);
    }
    if (lane < 16) {
#pragma unroll
      for (int ni = 0; ni < 4; ++ni) atomicAdd(&VK[c0 + ni * 16 + lane], csum[ni]);
    }
  }
}

__global__ __launch_bounds__(256) void k_vloss(const float* __restrict__ VK, double* va) {
  __shared__ float red[4];
  int tid = threadIdx.x;
  int i = blockIdx.x * 256 + tid;
  float l = __logf(EPSf + VK[i] * (1.f / 8192.f));
#pragma unroll
  for (int off = 32; off; off >>= 1) l += __shfl_down(l, off);
  if ((tid & 63) == 0) red[tid >> 6] = l;
  __syncthreads();
  if (tid == 0) {
    double tot = (double)red[0] + (double)red[1] + (double)red[2] + (double)red[3];
    atomicAdd(va, -tot / 8192.0);
  }
}

// Per-label symmetric Gram on fp8 Ehat', split-K. Tile pair (ti<=tj), 128x128,
// BK=64 (8B staging loads — no spill); LDS: LROW=80, chunks K-permuted
// [c0,c4,c1,c5,c2,c6,c3,c7] so lane (m,quad) reads BOTH ks fragments with one
// ds_read_b128 at row*80+quad*16 (bank starts 20m+4q: uniform, minimal).
__global__ __launch_bounds__(256, 4) void k_gram(const unsigned char* __restrict__ Eh,
                                                 const int* __restrict__ cnt,
                                                 const int* __restrict__ offs,
                                                 unsigned short* __restrict__ Spart) {
  int gid = blockIdx.x;                // 0..1439
  int xcd = gid & 7, slot = gid >> 3;  // slot 0..179
  int group = xcd * 5 + slot / NPAIR;  // 0..39
  int pidx = slot % NPAIR;
  int lab = group / SPLIT, split = group % SPLIT;
  int tj = 0;
  while ((tj + 1) * (tj + 2) / 2 <= pidx) ++tj;
  int ti = pidx - tj * (tj + 1) / 2;
  int c = cnt[lab], o = offs[lab];
  if (tj * 128 >= c) return;
  const bool diag = (ti == tj);
  __shared__ __align__(16) unsigned char Pt[128 * LROW];
  __shared__ __align__(16) unsigned char Rt[128 * LROW];
  int tid = threadIdx.x;
  int wave = tid >> 6, lane = tid & 63;
  int wrow = wave >> 1, wcol = wave & 1;
  int m = lane & 15, quad = lane >> 4;
  const unsigned char* pp[4];
  const unsigned char* pr[4];
  int lo[4];
#pragma unroll
  for (int v = 0; v < 4; ++v) {
    int slotv = v * 256 + tid, row = slotv >> 3, c8 = slotv & 7;
    int ri = o + ti * 128 + row; if (ri > NROW - 1) ri = NROW - 1;
    int rj = o + tj * 128 + row; if (rj > NROW - 1) rj = NROW - 1;
    pp[v] = Eh + (size_t)ri * NROW + split * 2048 + c8 * 8;
    pr[v] = Eh + (size_t)rj * NROW + split * 2048 + c8 * 8;
    int pos = (c8 & 3) * 2 + (c8 >> 2);  // K-permutation [c0,c4,c1,c5,c2,c6,c3,c7]
    lo[v] = row * LROW + pos * 8;
  }
  f32x4 acc[4][4];
#pragma unroll
  for (int mi = 0; mi < 4; ++mi)
#pragma unroll
    for (int ni = 0; ni < 4; ++ni) acc[mi][ni] = (f32x4){0.f, 0.f, 0.f, 0.f};
  const unsigned char* Bt = diag ? Pt : Rt;
  for (int t = 0; t < 32; ++t) {
    __syncthreads();
    unsigned long dp[4], dr[4];
#pragma unroll
    for (int v = 0; v < 4; ++v) {
      dp[v] = *(const unsigned long*)(pp[v]); pp[v] += 64;
      if (!diag) { dr[v] = *(const unsigned long*)(pr[v]); pr[v] += 64; }
    }
#pragma unroll
    for (int v = 0; v < 4; ++v) {
      *(unsigned long*)(Pt + lo[v]) = dp[v];
      if (!diag) *(unsigned long*)(Rt + lo[v]) = dr[v];
    }
    __syncthreads();
    longx2 pa[4], rb[4];
#pragma unroll
    for (int mi = 0; mi < 4; ++mi) {
      int row = wrow * 64 + mi * 16 + m;
      pa[mi] = *(const longx2*)(Pt + row * LROW + quad * 16);
    }
#pragma unroll
    for (int ni = 0; ni < 4; ++ni) {
      int row = wcol * 64 + ni * 16 + m;
      rb[ni] = *(const longx2*)(Bt + row * LROW + quad * 16);
    }
#pragma unroll
    for (int mi = 0; mi < 4; ++mi)
#pragma unroll
      for (int ni = 0; ni < 4; ++ni)
        acc[mi][ni] = __builtin_amdgcn_mfma_f32_16x16x32_fp8_fp8(pa[mi][0], rb[ni][0], acc[mi][ni], 0, 0, 0);
#pragma unroll
    for (int mi = 0; mi < 4; ++mi)
#pragma unroll
      for (int ni = 0; ni < 4; ++ni)
        acc[mi][ni] = __builtin_amdgcn_mfma_f32_16x16x32_fp8_fp8(pa[mi][1], rb[ni][1], acc[mi][ni], 0, 0, 0);
  }
  // layout: base + (mi*4+ni)*1024 + tid*4 + r  (ushort4-packed stores)
  size_t base = (size_t)(split * SPSTRIDE) + (size_t)(lab * NPAIR + pidx) * 16384;
#pragma unroll
  for (int mi = 0; mi < 4; ++mi)
#pragma unroll
    for (int ni = 0; ni < 4; ++ni) {
      ushort4 w4;
      w4.x = f2bf(acc[mi][ni][0]);
      w4.y = f2bf(acc[mi][ni][1]);
      w4.z = f2bf(acc[mi][ni][2]);
      w4.w = f2bf(acc[mi][ni][3]);
      *(ushort4*)(Spart + base + (size_t)(mi * 4 + ni) * 1024 + tid * 4) = w4;
    }
}

// Sum split partials, apply log(eps + S * ISE * LAM^-2), accumulate walker loss.
__global__ __launch_bounds__(256) void k_reduce(const unsigned short* __restrict__ Spart,
                                                const int* __restrict__ cnt,
                                                const int* __restrict__ offs,
                                                const float* __restrict__ CVs,
                                                double* wa) {
  int lab = blockIdx.y, pidx = blockIdx.x;
  int tj = 0;
  while ((tj + 1) * (tj + 2) / 2 <= pidx) ++tj;
  int ti = pidx - tj * (tj + 1) / 2;
  int c = cnt[lab], o = offs[lab];
  if (tj * 128 >= c) return;
  __shared__ float isei[128], isej[128];
  __shared__ float red[4];
  int tid = threadIdx.x;
  if (tid < 128) {
    int ri = o + ti * 128 + tid; if (ri > NROW - 1) ri = NROW - 1;
    int rj = o + tj * 128 + tid; if (rj > NROW - 1) rj = NROW - 1;
    isei[tid] = CVs[ri] * ILAM2;
    isej[tid] = CVs[rj] * ILAM2;
  }
  __syncthreads();
  int wave = tid >> 6, lane = tid & 63;
  int wrow = wave >> 1, wcol = wave & 1;
  int m = lane & 15, quad = lane >> 4;
  size_t base = (size_t)(lab * NPAIR + pidx) * 16384;
  float lsum = 0.f;
#pragma unroll
  for (int mi = 0; mi < 4; ++mi)
#pragma unroll
    for (int ni = 0; ni < 4; ++ni) {
      size_t off = base + (size_t)(mi * 4 + ni) * 1024 + tid * 4;
      ushort4 s0 = *(const ushort4*)(Spart + off);
      ushort4 s1 = *(const ushort4*)(Spart + SPSTRIDE + off);
      ushort4 s2 = *(const ushort4*)(Spart + 2 * (size_t)SPSTRIDE + off);
      ushort4 s3 = *(const ushort4*)(Spart + 3 * (size_t)SPSTRIDE + off);
      float S[4];
      S[0] = bf2f(s0.x) + bf2f(s1.x) + bf2f(s2.x) + bf2f(s3.x);
      S[1] = bf2f(s0.y) + bf2f(s1.y) + bf2f(s2.y) + bf2f(s3.y);
      S[2] = bf2f(s0.z) + bf2f(s1.z) + bf2f(s2.z) + bf2f(s3.z);
      S[3] = bf2f(s0.w) + bf2f(s1.w) + bf2f(s2.w) + bf2f(s3.w);
      int jl = wcol * 64 + ni * 16 + m;
      int j = tj * 128 + jl;
#pragma unroll
      for (int r = 0; r < 4; ++r) {
        int il = wrow * 64 + mi * 16 + quad * 4 + r;
        int i = ti * 128 + il;
        if (i < c && j < c) {
          lsum += __logf(EPSf + S[r] * isei[il]);
          if (ti != tj) lsum += __logf(EPSf + S[r] * isej[jl]);
        }
      }
    }
#pragma unroll
  for (int off2 = 32; off2; off2 >>= 1) lsum += __shfl_down(lsum, off2);
  if (lane == 0) red[wave] = lsum;
  __syncthreads();
  if (tid == 0) {
    double tot = (double)red[0] + (double)red[1] + (double)red[2] + (double)red[3];
    atomicAdd(wa, -tot / (8192.0 * (double)c));
  }
}

__global__ void k_finish(const double* wa, const double* va, float* out) {
  out[0] = (float)(*wa);
  out[1] = (float)(*va);
}

extern "C" void kernel_launch(void* const* d_in, const int* in_sizes, int n_in,
                              void* d_out, int out_size, void* d_ws, size_t ws_size,
                              hipStream_t stream) {
  const float* A = (const float*)d_in[0];
  const float* B = (const float*)d_in[1];
  const int* LAB = (const int*)d_in[2];
  float* out = (float*)d_out;
  char* w = (char*)d_ws;
  double* WA = (double*)(w + O_WA);
  double* VA = (double*)(w + O_VA);
  int* CNT = (int*)(w + O_CNT);
  int* OFFS = (int*)(w + O_OFF);
  int* SIDX = (int*)(w + O_SIDX);
  float* PS = (float*)(w + O_PS);
  float* CS = (float*)(w + O_CS);
  float* VK = (float*)(w + O_VK);
  float* CVs = (float*)(w + O_CV);
  float* CKS = (float*)(w + O_CKS);
  unsigned short* ABF = (unsigned short*)(w + O_ABF);
  unsigned short* BBF = (unsigned short*)(w + O_BBF);
  unsigned char* E = (unsigned char*)(w + O_E);
  unsigned short* SP = (unsigned short*)(w + O_SP);

  k_bucket<<<1, 256, 0, stream>>>(LAB, CNT, OFFS, SIDX, WA, VA, CS, VK);
  k_convert<<<512, 256, 0, stream>>>(A, ABF);
  k_convert<<<512, 256, 0, stream>>>(B, BBF);
  k_stats<<<dim3(64, 16), 256, 0, stream>>>(ABF, BBF, SIDX, PS, CS);
  k_mstats<<<32, 256, 0, stream>>>(PS, CS, CVs, CKS);
  k_fill<<<dim3(64, 16), 256, 0, stream>>>(ABF, BBF, SIDX, CVs, CKS, E, VK);
  k_vloss<<<32, 256, 0, stream>>>(VK, VA);
  k_gram<<<NPAIR * SPLIT * NLAB, 256, 0, stream>>>(E, CNT, OFFS, SP);
  k_reduce<<<dim3(NPAIR, NLAB), 256, 0, stream>>>(SP, CNT, OFFS, CVs, WA);
  k_finish<<<1, 1, 0, stream>>>(WA, VA, out);
}

// Round 15
// 271.210 us; speedup vs baseline: 1.4755x; 1.0943x over previous
//
#include <hip/hip_runtime.h>

// WalkerVisitLosses, round 15.
// E = exp2(A'.B'^T) (A'=A*SF, SF^2=log2(e)/sqrt(128)); SE_i row sums,
// CS_k col sums. Ehat' = E*rsqrt(CS)*64 in fp8 e4m3; S = Ehat'.Ehat'^T;
// walker log(eps + S*(1/SE)*2^-12) on same-label tile pairs; visit from E/SE.
// Round-15 (k_gram only): adopt the r7/r9 HW-verified ZERO-conflict LDS
// geometry (128B rows, 8x16B slots, slot^=(L&7), b128 access) by pairing
// fp8 tile-rows: LDS row L = tile-rows {2L,2L+1}. One b128 read gives both
// K=32 fragments (consistent A/B K-chunk pairing => dot unchanged).
// Staging = 2x16B contiguous loads/thread (16 live VGPRs, r10-level, no
// spill). r10 xor-b64 / r12 pad-b64 / r14 perm-b128 all conflicted ~1e7.

typedef __attribute__((ext_vector_type(8))) short bf16x8;
typedef __attribute__((ext_vector_type(4))) float f32x4;
typedef __attribute__((ext_vector_type(2))) long longx2;

#define NROW 8192
#define DIM 128
#define NLAB 10
#define EPSf 1e-8f
#define SF 0.35709582f /* sqrt( log2(e)/sqrt(128) ) */
#define LAM 64.0f      /* fp8 range-centering scale; LAM^-2 folded into ISE */
#define ILAM2 (1.0f / 4096.0f)
#define SPLIT 4
#define NPAIR 36   /* supports up to 8 row-tiles per label */
#define SPSTRIDE (360 * 16384) /* elements per split */

// workspace byte offsets (total ~120 MB)
#define O_WA 0
#define O_VA 8
#define O_CNT 64
#define O_OFF 128
#define O_SIDX 256
#define O_PS 33280
#define O_CS 1081856
#define O_VK 1114624
#define O_CV 1147392
#define O_CKS 1180160
#define O_ABF 1212928
#define O_BBF 3310080
#define O_E 5407232            /* fp8: 64 MB */
#define O_SP 72516096

__device__ __forceinline__ unsigned short f2bf(float f) {
  unsigned u = __builtin_bit_cast(unsigned, f);
  u += 0x7fffu + ((u >> 16) & 1u);
  return (unsigned short)(u >> 16);
}
__device__ __forceinline__ float bf2f(unsigned short s) {
  unsigned u = ((unsigned)s) << 16;
  return __builtin_bit_cast(float, u);
}
__device__ __forceinline__ unsigned char f2fp8(float f) {
  int v = __builtin_amdgcn_cvt_pk_fp8_f32(f, f, 0, false);
  return (unsigned char)(v & 0xff);
}

__global__ __launch_bounds__(256) void k_bucket(const int* __restrict__ lab,
                                                int* cnt, int* offs, int* sidx,
                                                double* wa, double* va,
                                                float* cs, float* vk) {
  __shared__ int lc[NLAB], lcur[NLAB];
  int tid = threadIdx.x;
  if (tid < NLAB) lc[tid] = 0;
  __syncthreads();
  for (int i = tid; i < NROW; i += 256) {
    int l = lab[i]; l = l < 0 ? 0 : (l > 9 ? 9 : l);
    atomicAdd(&lc[l], 1);
  }
  for (int i = tid; i < NROW; i += 256) { cs[i] = 0.f; vk[i] = 0.f; }
  __syncthreads();
  if (tid == 0) {
    int run = 0;
    for (int l = 0; l < NLAB; ++l) { cnt[l] = lc[l]; offs[l] = run; lcur[l] = run; run += lc[l]; }
    *wa = 0.0; *va = 0.0;
  }
  __syncthreads();
  for (int i = tid; i < NROW; i += 256) {
    int l = lab[i]; l = l < 0 ? 0 : (l > 9 ? 9 : l);
    int p = atomicAdd(&lcur[l], 1);
    sidx[p] = i;
  }
}

__global__ __launch_bounds__(256) void k_convert(const float* __restrict__ X,
                                                 unsigned short* __restrict__ Y) {
  int i = (blockIdx.x * 256 + threadIdx.x) * 8;
  f32x4 a = *(const f32x4*)(X + i);
  f32x4 b = *(const f32x4*)(X + i + 4);
  bf16x8 o;
  o[0] = (short)f2bf(a[0] * SF); o[1] = (short)f2bf(a[1] * SF);
  o[2] = (short)f2bf(a[2] * SF); o[3] = (short)f2bf(a[3] * SF);
  o[4] = (short)f2bf(b[0] * SF); o[5] = (short)f2bf(b[1] * SF);
  o[6] = (short)f2bf(b[2] * SF); o[7] = (short)f2bf(b[3] * SF);
  *(bf16x8*)(Y + i) = o;
}

// Pass 1: GEMM+exp only -> row partial sums (ps, 32 slices) + col sums (atomic).
// Round-12 form: hoisted af[4][4], ks-inner.
__global__ __launch_bounds__(256, 2) void k_stats(const unsigned short* __restrict__ Abf,
                                                  const unsigned short* __restrict__ Bbf,
                                                  const int* __restrict__ sidx,
                                                  float* __restrict__ ps,
                                                  float* __restrict__ CS) {
  __shared__ int gidx[128];
  int tid = threadIdx.x;
  if (tid < 128) gidx[tid] = sidx[blockIdx.x * 128 + tid];
  __syncthreads();
  int wave = tid >> 6, lane = tid & 63;
  int wrow = wave >> 1, wcol = wave & 1;
  int m = lane & 15, quad = lane >> 4;
  bf16x8 af[4][4];
#pragma unroll
  for (int mi = 0; mi < 4; ++mi) {
    int gi = gidx[wrow * 64 + mi * 16 + m];
#pragma unroll
    for (int ks = 0; ks < 4; ++ks)
      af[mi][ks] = *(const bf16x8*)(Abf + gi * DIM + ks * 32 + quad * 8);
  }
  float tsum[4][4];
#pragma unroll
  for (int mi = 0; mi < 4; ++mi)
#pragma unroll
    for (int r = 0; r < 4; ++r) tsum[mi][r] = 0.f;
  int p0 = blockIdx.x * 128 + wrow * 64;
  for (int t = 0; t < 4; ++t) {
    int c0 = blockIdx.y * 512 + t * 128 + wcol * 64;
    bf16x8 bfr[4][4];
#pragma unroll
    for (int ni = 0; ni < 4; ++ni)
#pragma unroll
      for (int ks = 0; ks < 4; ++ks)
        bfr[ni][ks] = *(const bf16x8*)(Bbf + (c0 + ni * 16 + m) * DIM + ks * 32 + quad * 8);
    f32x4 acc[4][4];
#pragma unroll
    for (int mi = 0; mi < 4; ++mi)
#pragma unroll
      for (int ni = 0; ni < 4; ++ni) acc[mi][ni] = (f32x4){0.f, 0.f, 0.f, 0.f};
#pragma unroll
    for (int ks = 0; ks < 4; ++ks)
#pragma unroll
      for (int mi = 0; mi < 4; ++mi)
#pragma unroll
        for (int ni = 0; ni < 4; ++ni)
          acc[mi][ni] = __builtin_amdgcn_mfma_f32_16x16x32_bf16(af[mi][ks], bfr[ni][ks], acc[mi][ni], 0, 0, 0);
    float csum[4] = {0.f, 0.f, 0.f, 0.f};
#pragma unroll
    for (int mi = 0; mi < 4; ++mi)
#pragma unroll
      for (int ni = 0; ni < 4; ++ni)
#pragma unroll
        for (int r = 0; r < 4; ++r) {
          float e = __builtin_amdgcn_exp2f(acc[mi][ni][r]);
          tsum[mi][r] += e;
          csum[ni] += e;
        }
#pragma unroll
    for (int ni = 0; ni < 4; ++ni) {
      csum[ni] += __shfl_xor(csum[ni], 16);
      csum[ni] += __shfl_xor(csum[ni], 32);
    }
    if (lane < 16) {
#pragma unroll
      for (int ni = 0; ni < 4; ++ni) atomicAdd(&CS[c0 + ni * 16 + lane], csum[ni]);
    }
  }
#pragma unroll
  for (int off = 1; off < 16; off <<= 1)
#pragma unroll
    for (int mi = 0; mi < 4; ++mi)
#pragma unroll
      for (int r = 0; r < 4; ++r) tsum[mi][r] += __shfl_xor(tsum[mi][r], off);
  if (m == 0) {
#pragma unroll
    for (int mi = 0; mi < 4; ++mi)
#pragma unroll
      for (int r = 0; r < 4; ++r)
        ps[(blockIdx.y * 2 + wcol) * NROW + p0 + mi * 16 + quad * 4 + r] = tsum[mi][r];
  }
}

__global__ __launch_bounds__(256) void k_mstats(const float* __restrict__ ps,
                                                const float* __restrict__ CS,
                                                float* __restrict__ CVs,
                                                float* __restrict__ CKS) {
  int i = blockIdx.x * 256 + threadIdx.x;
  float s = 0.f;
#pragma unroll
  for (int t = 0; t < 32; ++t) s += ps[t * NROW + i];
  CVs[i] = 1.f / s;
  CKS[i] = rsqrtf(CS[i]);
}

// Pass 2: recompute GEMM+exp, write Ehat*LAM as fp8 e4m3 (sorted rows),
// accumulate raw visit VK[k] += E*CV[row]. Round-12 form.
__global__ __launch_bounds__(256, 2) void k_fill(const unsigned short* __restrict__ Abf,
                                                 const unsigned short* __restrict__ Bbf,
                                                 const int* __restrict__ sidx,
                                                 const float* __restrict__ CVs,
                                                 const float* __restrict__ CKS,
                                                 unsigned char* __restrict__ E,
                                                 float* __restrict__ VK) {
  __shared__ int gidx[128];
  int tid = threadIdx.x;
  if (tid < 128) gidx[tid] = sidx[blockIdx.x * 128 + tid];
  __syncthreads();
  int wave = tid >> 6, lane = tid & 63;
  int wrow = wave >> 1, wcol = wave & 1;
  int m = lane & 15, quad = lane >> 4;
  int p0 = blockIdx.x * 128 + wrow * 64;
  bf16x8 af[4][4];
  float cv16[4][4];
#pragma unroll
  for (int mi = 0; mi < 4; ++mi) {
    int gi = gidx[wrow * 64 + mi * 16 + m];
#pragma unroll
    for (int ks = 0; ks < 4; ++ks)
      af[mi][ks] = *(const bf16x8*)(Abf + gi * DIM + ks * 32 + quad * 8);
#pragma unroll
    for (int r = 0; r < 4; ++r) cv16[mi][r] = CVs[p0 + mi * 16 + quad * 4 + r];
  }
  for (int t = 0; t < 4; ++t) {
    int c0 = blockIdx.y * 512 + t * 128 + wcol * 64;
    bf16x8 bfr[4][4];
    float ck4[4];
#pragma unroll
    for (int ni = 0; ni < 4; ++ni) {
      ck4[ni] = CKS[c0 + ni * 16 + m] * LAM;
#pragma unroll
      for (int ks = 0; ks < 4; ++ks)
        bfr[ni][ks] = *(const bf16x8*)(Bbf + (c0 + ni * 16 + m) * DIM + ks * 32 + quad * 8);
    }
    f32x4 acc[4][4];
#pragma unroll
    for (int mi = 0; mi < 4; ++mi)
#pragma unroll
      for (int ni = 0; ni < 4; ++ni) acc[mi][ni] = (f32x4){0.f, 0.f, 0.f, 0.f};
#pragma unroll
    for (int ks = 0; ks < 4; ++ks)
#pragma unroll
      for (int mi = 0; mi < 4; ++mi)
#pragma unroll
        for (int ni = 0; ni < 4; ++ni)
          acc[mi][ni] = __builtin_amdgcn_mfma_f32_16x16x32_bf16(af[mi][ks], bfr[ni][ks], acc[mi][ni], 0, 0, 0);
    float csum[4] = {0.f, 0.f, 0.f, 0.f};
#pragma unroll
    for (int mi = 0; mi < 4; ++mi)
#pragma unroll
      for (int ni = 0; ni < 4; ++ni)
#pragma unroll
        for (int r = 0; r < 4; ++r) {
          float e = __builtin_amdgcn_exp2f(acc[mi][ni][r]);
          int row = p0 + mi * 16 + quad * 4 + r;
          E[(size_t)row * NROW + c0 + ni * 16 + m] = f2fp8(e * ck4[ni]);
          csum[ni] = fmaf(e, cv16[mi][r], csum[ni]);
        }
#pragma unroll
    for (int ni = 0; ni < 4; ++ni) {
      csum[ni] += __shfl_xor(csum[ni], 16);
      csum[ni] += __shfl_xor(csum[ni], 32);
    }
    if (lane < 16) {
#pragma unroll
      for (int ni = 0; ni < 4; ++ni) atomicAdd(&VK[c0 + ni * 16 + lane], csum[ni]);
    }
  }
}

__global__ __launch_bounds__(256) void k_vloss(const float* __restrict__ VK, double* va) {
  __shared__ float red[4];
  int tid = threadIdx.x;
  int i = blockIdx.x * 256 + tid;
  float l = __logf(EPSf + VK[i] * (1.f / 8192.f));
#pragma unroll
  for (int off = 32; off; off >>= 1) l += __shfl_down(l, off);
  if ((tid & 63) == 0) red[tid >> 6] = l;
  __syncthreads();
  if (tid == 0) {
    double tot = (double)red[0] + (double)red[1] + (double)red[2] + (double)red[3];
    atomicAdd(va, -tot / 8192.0);
  }
}

// Per-label symmetric Gram on fp8 Ehat', split-K. Tile pair (ti<=tj), 128x128,
// BK=64. LDS: r7-verified geometry — 64 rows x 128B, 8x16B slots,
// slot ^= (L&7), b128 access only. LDS row L = tile-rows {2L, 2L+1}.
// One b128 read = both K-fragments (A/B K-chunk pairing consistent).
__global__ __launch_bounds__(256, 4) void k_gram(const unsigned char* __restrict__ Eh,
                                                 const int* __restrict__ cnt,
                                                 const int* __restrict__ offs,
                                                 unsigned short* __restrict__ Spart) {
  int gid = blockIdx.x;                // 0..1439
  int xcd = gid & 7, slot = gid >> 3;  // slot 0..179
  int group = xcd * 5 + slot / NPAIR;  // 0..39
  int pidx = slot % NPAIR;
  int lab = group / SPLIT, split = group % SPLIT;
  int tj = 0;
  while ((tj + 1) * (tj + 2) / 2 <= pidx) ++tj;
  int ti = pidx - tj * (tj + 1) / 2;
  int c = cnt[lab], o = offs[lab];
  if (tj * 128 >= c) return;
  const bool diag = (ti == tj);
  __shared__ __align__(16) unsigned char Pt[64 * 128];
  __shared__ __align__(16) unsigned char Rt[64 * 128];
  int tid = threadIdx.x;
  int wave = tid >> 6, lane = tid & 63;
  int wrow = wave >> 1, wcol = wave & 1;
  int m = lane & 15, quad = lane >> 4;
  const unsigned char* pp[2];
  const unsigned char* pr[2];
  int lo[2];
#pragma unroll
  for (int v = 0; v < 2; ++v) {
    int sIdx = v * 256 + tid;          // 0..511 slots (16B each)
    int tr = sIdx >> 2, q = sIdx & 3;  // tile-row, 16B chunk
    int ri = o + ti * 128 + tr; if (ri > NROW - 1) ri = NROW - 1;
    int rj = o + tj * 128 + tr; if (rj > NROW - 1) rj = NROW - 1;
    pp[v] = Eh + (size_t)ri * NROW + split * 2048 + q * 16;
    pr[v] = Eh + (size_t)rj * NROW + split * 2048 + q * 16;
    int L = tr >> 1, p = tr & 1;
    lo[v] = L * 128 + ((((p << 2) | q) ^ (L & 7)) * 16);
  }
  // frag read offsets (fixed per lane)
  int ro[4];  // for mi (A) — same formula for ni (B) since wrow/wcol differ
  f32x4 acc[4][4];
#pragma unroll
  for (int mi = 0; mi < 4; ++mi)
#pragma unroll
    for (int ni = 0; ni < 4; ++ni) acc[mi][ni] = (f32x4){0.f, 0.f, 0.f, 0.f};
  const unsigned char* Bt = diag ? Pt : Rt;
  for (int t = 0; t < 32; ++t) {
    __syncthreads();
    longx2 dp[2], dr[2];
#pragma unroll
    for (int v = 0; v < 2; ++v) {
      dp[v] = *(const longx2*)(pp[v]); pp[v] += 64;
      if (!diag) { dr[v] = *(const longx2*)(pr[v]); pr[v] += 64; }
    }
#pragma unroll
    for (int v = 0; v < 2; ++v) {
      *(longx2*)(Pt + lo[v]) = dp[v];
      if (!diag) *(longx2*)(Rt + lo[v]) = dr[v];
    }
    __syncthreads();
    longx2 pa[4], rb[4];
#pragma unroll
    for (int mi = 0; mi < 4; ++mi) {
      int tr = wrow * 64 + mi * 16 + m;
      int L = tr >> 1, p = tr & 1;
      pa[mi] = *(const longx2*)(Pt + L * 128 + ((((p << 2) | quad) ^ (L & 7)) * 16));
    }
#pragma unroll
    for (int ni = 0; ni < 4; ++ni) {
      int tr = wcol * 64 + ni * 16 + m;
      int L = tr >> 1, p = tr & 1;
      rb[ni] = *(const longx2*)(Bt + L * 128 + ((((p << 2) | quad) ^ (L & 7)) * 16));
    }
#pragma unroll
    for (int mi = 0; mi < 4; ++mi)
#pragma unroll
      for (int ni = 0; ni < 4; ++ni)
        acc[mi][ni] = __builtin_amdgcn_mfma_f32_16x16x32_fp8_fp8(pa[mi][0], rb[ni][0], acc[mi][ni], 0, 0, 0);
#pragma unroll
    for (int mi = 0; mi < 4; ++mi)
#pragma unroll
      for (int ni = 0; ni < 4; ++ni)
        acc[mi][ni] = __builtin_amdgcn_mfma_f32_16x16x32_fp8_fp8(pa[mi][1], rb[ni][1], acc[mi][ni], 0, 0, 0);
  }
  (void)ro;
  // layout: base + (mi*4+ni)*1024 + tid*4 + r  (ushort4-packed stores)
  size_t base = (size_t)(split * SPSTRIDE) + (size_t)(lab * NPAIR + pidx) * 16384;
#pragma unroll
  for (int mi = 0; mi < 4; ++mi)
#pragma unroll
    for (int ni = 0; ni < 4; ++ni) {
      ushort4 w4;
      w4.x = f2bf(acc[mi][ni][0]);
      w4.y = f2bf(acc[mi][ni][1]);
      w4.z = f2bf(acc[mi][ni][2]);
      w4.w = f2bf(acc[mi][ni][3]);
      *(ushort4*)(Spart + base + (size_t)(mi * 4 + ni) * 1024 + tid * 4) = w4;
    }
}

// Sum split partials, apply log(eps + S * ISE * LAM^-2), accumulate walker loss.
__global__ __launch_bounds__(256) void k_reduce(const unsigned short* __restrict__ Spart,
                                                const int* __restrict__ cnt,
                                                const int* __restrict__ offs,
                                                const float* __restrict__ CVs,
                                                double* wa) {
  int lab = blockIdx.y, pidx = blockIdx.x;
  int tj = 0;
  while ((tj + 1) * (tj + 2) / 2 <= pidx) ++tj;
  int ti = pidx - tj * (tj + 1) / 2;
  int c = cnt[lab], o = offs[lab];
  if (tj * 128 >= c) return;
  __shared__ float isei[128], isej[128];
  __shared__ float red[4];
  int tid = threadIdx.x;
  if (tid < 128) {
    int ri = o + ti * 128 + tid; if (ri > NROW - 1) ri = NROW - 1;
    int rj = o + tj * 128 + tid; if (rj > NROW - 1) rj = NROW - 1;
    isei[tid] = CVs[ri] * ILAM2;
    isej[tid] = CVs[rj] * ILAM2;
  }
  __syncthreads();
  int wave = tid >> 6, lane = tid & 63;
  int wrow = wave >> 1, wcol = wave & 1;
  int m = lane & 15, quad = lane >> 4;
  size_t base = (size_t)(lab * NPAIR + pidx) * 16384;
  float lsum = 0.f;
#pragma unroll
  for (int mi = 0; mi < 4; ++mi)
#pragma unroll
    for (int ni = 0; ni < 4; ++ni) {
      size_t off = base + (size_t)(mi * 4 + ni) * 1024 + tid * 4;
      ushort4 s0 = *(const ushort4*)(Spart + off);
      ushort4 s1 = *(const ushort4*)(Spart + SPSTRIDE + off);
      ushort4 s2 = *(const ushort4*)(Spart + 2 * (size_t)SPSTRIDE + off);
      ushort4 s3 = *(const ushort4*)(Spart + 3 * (size_t)SPSTRIDE + off);
      float S[4];
      S[0] = bf2f(s0.x) + bf2f(s1.x) + bf2f(s2.x) + bf2f(s3.x);
      S[1] = bf2f(s0.y) + bf2f(s1.y) + bf2f(s2.y) + bf2f(s3.y);
      S[2] = bf2f(s0.z) + bf2f(s1.z) + bf2f(s2.z) + bf2f(s3.z);
      S[3] = bf2f(s0.w) + bf2f(s1.w) + bf2f(s2.w) + bf2f(s3.w);
      int jl = wcol * 64 + ni * 16 + m;
      int j = tj * 128 + jl;
#pragma unroll
      for (int r = 0; r < 4; ++r) {
        int il = wrow * 64 + mi * 16 + quad * 4 + r;
        int i = ti * 128 + il;
        if (i < c && j < c) {
          lsum += __logf(EPSf + S[r] * isei[il]);
          if (ti != tj) lsum += __logf(EPSf + S[r] * isej[jl]);
        }
      }
    }
#pragma unroll
  for (int off2 = 32; off2; off2 >>= 1) lsum += __shfl_down(lsum, off2);
  if (lane == 0) red[wave] = lsum;
  __syncthreads();
  if (tid == 0) {
    double tot = (double)red[0] + (double)red[1] + (double)red[2] + (double)red[3];
    atomicAdd(wa, -tot / (8192.0 * (double)c));
  }
}

__global__ void k_finish(const double* wa, const double* va, float* out) {
  out[0] = (float)(*wa);
  out[1] = (float)(*va);
}

extern "C" void kernel_launch(void* const* d_in, const int* in_sizes, int n_in,
                              void* d_out, int out_size, void* d_ws, size_t ws_size,
                              hipStream_t stream) {
  const float* A = (const float*)d_in[0];
  const float* B = (const float*)d_in[1];
  const int* LAB = (const int*)d_in[2];
  float* out = (float*)d_out;
  char* w = (char*)d_ws;
  double* WA = (double*)(w + O_WA);
  double* VA = (double*)(w + O_VA);
  int* CNT = (int*)(w + O_CNT);
  int* OFFS = (int*)(w + O_OFF);
  int* SIDX = (int*)(w + O_SIDX);
  float* PS = (float*)(w + O_PS);
  float* CS = (float*)(w + O_CS);
  float* VK = (float*)(w + O_VK);
  float* CVs = (float*)(w + O_CV);
  float* CKS = (float*)(w + O_CKS);
  unsigned short* ABF = (unsigned short*)(w + O_ABF);
  unsigned short* BBF = (unsigned short*)(w + O_BBF);
  unsigned char* E = (unsigned char*)(w + O_E);
  unsigned short* SP = (unsigned short*)(w + O_SP);

  k_bucket<<<1, 256, 0, stream>>>(LAB, CNT, OFFS, SIDX, WA, VA, CS, VK);
  k_convert<<<512, 256, 0, stream>>>(A, ABF);
  k_convert<<<512, 256, 0, stream>>>(B, BBF);
  k_stats<<<dim3(64, 16), 256, 0, stream>>>(ABF, BBF, SIDX, PS, CS);
  k_mstats<<<32, 256, 0, stream>>>(PS, CS, CVs, CKS);
  k_fill<<<dim3(64, 16), 256, 0, stream>>>(ABF, BBF, SIDX, CVs, CKS, E, VK);
  k_vloss<<<32, 256, 0, stream>>>(VK, VA);
  k_gram<<<NPAIR * SPLIT * NLAB, 256, 0, stream>>>(E, CNT, OFFS, SP);
  k_reduce<<<dim3(NPAIR, NLAB), 256, 0, stream>>>(SP, CNT, OFFS, CVs, WA);
  k_finish<<<1, 1, 0, stream>>>(WA, VA, out);
}